// Round 12
// baseline (477.318 us; speedup 1.0000x reference)
//
#include <hip/hip_runtime.h>

#define N_ROWS 65536
#define K_CODES 4096
#define D_DIM 256
#define MARGIN_BF 4.5e-5f
#define CAP_DUEL 24576
#define CAP_FULL 8192

typedef __attribute__((ext_vector_type(8))) _Float16 f16x8;
typedef __attribute__((ext_vector_type(4))) float f32x4;

// ---------------- ws layout ----------------
// [0]        float  rownorm[65536]      256 KB
// [262144]   float  cvec[4096]           16 KB
// [278528]   ushort emb_perm[4096*256]    2 MB   (f16 x4096, B-frag stream-linear)
// [2375680]  int    cnts[2]  (0=duel, 1=full)
// [2375936]  int    fulllist[8192]       32 KB
// [2408704]  u64    duellist[24576]     192 KB
// [2605312]  u64    rescored[65536]     512 KB
// [3129600]  double partials[2048]       16 KB
// z_perm (33.5 MB) lives in d_out as scratch; writeback overwrites d_out fully.

union f16u { _Float16 h; unsigned short u; };

static __device__ __forceinline__ unsigned int pack2(float a, float b) {
    f16u x, y; x.h = (_Float16)a; y.h = (_Float16)b;
    return (unsigned)x.u | ((unsigned)y.u << 16);
}

// ---------------- r2-verified norm chain (verbatim body, block-offset) ----------------
static __device__ __forceinline__ void norm_body(const float* __restrict__ src,
                                                 float* __restrict__ dst, int bi, int tid) {
    int row = bi * 64 + (tid >> 2);
    int q = tid & 3;
    const float* p = src + (size_t)row * D_DIM;
    double acc = 0.0;
#pragma unroll 4
    for (int it = 0; it < 16; ++it) {
        float4 v = *(const float4*)&p[(q + 4 * it) * 4];
        float a = v.x * v.x, b = v.y * v.y, c = v.z * v.z, d = v.w * v.w;
        acc += (double)a; acc += (double)b; acc += (double)c; acc += (double)d;
    }
    acc += __shfl_xor(acc, 1);
    acc += __shfl_xor(acc, 2);
    if (q == 0) dst[row] = (float)acc;
}

// ---------------- emb -> f16(x4096), B-frag stream-linear + emb-norm + cnt clear ----------------
__global__ __launch_bounds__(256) void cvt_emb_kernel(const float* __restrict__ emb,
                                                      unsigned short* __restrict__ emb_perm,
                                                      float* __restrict__ cvec,
                                                      int* __restrict__ cnts) {
    if (blockIdx.x >= 512) {
        if (blockIdx.x == 512 && threadIdx.x < 2) cnts[threadIdx.x] = 0;
        norm_body(emb, cvec, blockIdx.x - 512, threadIdx.x);
        return;
    }
    int gid = blockIdx.x * 256 + threadIdx.x;     // 131072 16B units
    int lane = gid & 63;
    int f = gid >> 6;
    int cf = f & 1;
    int d8 = (f >> 1) & 7;
    int step = (f >> 4) & 63;
    int h = f >> 10;
    int code = h * 2048 + step * 32 + cf * 16 + (lane & 15);
    int d0 = d8 * 32 + (lane >> 4) * 8;
    const float* p = emb + (size_t)code * D_DIM + d0;
    float4 v0 = *(const float4*)p;
    float4 v1 = *(const float4*)(p + 4);
    uint4 o;
    o.x = pack2(v0.x * 4096.0f, v0.y * 4096.0f);
    o.y = pack2(v0.z * 4096.0f, v0.w * 4096.0f);
    o.z = pack2(v1.x * 4096.0f, v1.y * 4096.0f);
    o.w = pack2(v1.z * 4096.0f, v1.w * 4096.0f);
    *(uint4*)((char*)emb_perm + (size_t)gid * 16) = o;
}

// ---------------- z -> f16 fragment-linear + z-norm + rescored clear (r11-verified) ----------------
__global__ __launch_bounds__(256) void cvt_z_kernel(const float* __restrict__ z,
                                                    unsigned short* __restrict__ z_perm,
                                                    float* __restrict__ rownorm,
                                                    unsigned long long* __restrict__ rescored) {
    if (blockIdx.x >= 8192) {
        norm_body(z, rownorm, blockIdx.x - 8192, threadIdx.x);
        return;
    }
    if (blockIdx.x < 256) rescored[blockIdx.x * 256 + threadIdx.x] = ~0ull;
    int ft = blockIdx.x * 256 + threadIdx.x;      // 2097152 frag-lanes
    int lane = ft & 63;
    int rf = (ft >> 6) & 3;
    int d8 = (ft >> 8) & 7;
    int rg = ft >> 11;
    int row = rg * 64 + rf * 16 + (lane & 15);
    int d0 = d8 * 32 + (lane >> 4) * 8;
    const float* p = z + (size_t)row * D_DIM + d0;
    float4 v0 = *(const float4*)p;
    float4 v1 = *(const float4*)(p + 4);
    uint4 o;
    o.x = pack2(v0.x, v0.y);
    o.y = pack2(v0.z, v0.w);
    o.z = pack2(v1.x, v1.y);
    o.w = pack2(v1.z, v1.w);
    *(uint4*)((char*)z_perm + (size_t)ft * 16) = o;
}

// ---------------- phase B: B-streaming f16 MFMA argmin with top-3 tracking ----------------
__global__ __launch_bounds__(256, 2) void phaseB_kernel(
        const unsigned short* __restrict__ z_perm, const unsigned short* __restrict__ emb_perm,
        const float* __restrict__ cvec, float* __restrict__ out_idx,
        int* __restrict__ cnts, int* __restrict__ fulllist,
        unsigned long long* __restrict__ duellist) {
    __shared__ float cv[4096];     // 16 KB; reused as merge scratch after the loop

    const int tid = threadIdx.x;
    const int lane = tid & 63;
    const int w = tid >> 6;
    const int pp = w >> 1;         // row group
    const int h = w & 1;           // code half
    const int l15 = lane & 15, l4 = lane >> 4;
    const int rb = blockIdx.x;     // 512 blocks x 128 rows

    // ---- cvec -> LDS ----
#pragma unroll
    for (int i = 0; i < 4; ++i) {
        int idx = i * 1024 + tid * 4;
        *(float4*)&cv[idx] = *(const float4*)&cvec[idx];
    }

    // ---- A (64 rows) into registers (AGPR-eligible): 32 frags ----
    f16x8 A[8][4];
    {
        const char* zsrc = (const char*)z_perm + (size_t)(rb * 2 + pp) * 32768 + lane * 16;
#pragma unroll
        for (int d8 = 0; d8 < 8; ++d8)
#pragma unroll
            for (int rf = 0; rf < 4; ++rf)
                A[d8][rf] = *(const f16x8*)(zsrc + (d8 * 4 + rf) * 1024);
    }
    __syncthreads();               // cv ready

    // ---- B stream: 2-slot ring, depth-1 prefetch (pair p = step*8 + d8) ----
    const char* bq = (const char*)emb_perm + (size_t)h * 1048576 + lane * 16;
    f16x8 B0a, B0b, B1a, B1b;
    B0a = *(const f16x8*)(bq);
    B0b = *(const f16x8*)(bq + 1024);

    float m1[16], m2[16], m3[16];
    int i1[16], i2[16];
#pragma unroll
    for (int t = 0; t < 16; ++t) {
        m1[t] = 3.4e38f; m2[t] = 3.4e38f; m3[t] = 3.4e38f; i1[t] = 0; i2[t] = 0;
    }

    f32x4 acc[4][2];

    for (int step = 0; step < 64; ++step) {
        const int kb = h * 2048 + step * 32;
        float ck0 = cv[kb + l15];
        float ck1 = cv[kb + 16 + l15];
#pragma unroll
        for (int rf = 0; rf < 4; ++rf) {
            acc[rf][0] = (f32x4){0.f, 0.f, 0.f, 0.f};
            acc[rf][1] = (f32x4){0.f, 0.f, 0.f, 0.f};
        }
        // Tail prefetch past the half (or buffer end) reads mapped ws bytes
        // into dead regs, never consumed. Safe.
#pragma unroll
        for (int d8 = 0; d8 < 8; ++d8) {
            const char* pf = bq + (d8 + 1) * 2048;
            f16x8 b0, b1;
            if (d8 & 1) {
                b0 = B1a; b1 = B1b;
                B0a = *(const f16x8*)pf; B0b = *(const f16x8*)(pf + 1024);
            } else {
                b0 = B0a; b1 = B0b;
                B1a = *(const f16x8*)pf; B1b = *(const f16x8*)(pf + 1024);
            }
#pragma unroll
            for (int rf = 0; rf < 4; ++rf) {
                acc[rf][0] = __builtin_amdgcn_mfma_f32_16x16x32_f16(A[d8][rf], b0, acc[rf][0], 0, 0, 0);
                acc[rf][1] = __builtin_amdgcn_mfma_f32_16x16x32_f16(A[d8][rf], b1, acc[rf][1], 0, 0, 0);
            }
        }
        bq += 16384;

        // ---- epilogue: running top-3 (values) + top-2 indices over 32 codes ----
#pragma unroll
        for (int cf = 0; cf < 2; ++cf) {
            float ck = cf ? ck1 : ck0;
            int codeg = kb + cf * 16 + l15;
#pragma unroll
            for (int rf = 0; rf < 4; ++rf)
#pragma unroll
                for (int j = 0; j < 4; ++j) {
                    // acc = z.(4096 e); -2*dot = acc * -2^-11 (exact scale)
                    float d = fmaf(-4.8828125e-4f, acc[rf][cf][j], ck);
                    const int t = rf * 4 + j;
                    bool lt1 = d < m1[t];
                    bool lt2 = d < m2[t];
                    m3[t] = __builtin_amdgcn_fmed3f(d, m2[t], m3[t]);
                    i2[t] = lt1 ? i1[t] : (lt2 ? codeg : i2[t]);
                    m2[t] = __builtin_amdgcn_fmed3f(d, m1[t], m2[t]);
                    i1[t] = lt1 ? codeg : i1[t];
                    m1[t] = fminf(m1[t], d);
                }
        }
    }

    // ---- per-wave merge across the 16 column-lanes (top-3 sorted-merge) ----
    __syncthreads();               // cv dead; reuse as merge scratch
    float* m1s = cv;               // [4][64]
    float* m2s = cv + 256;
    float* m3s = cv + 512;
    int*   i1s = (int*)(cv + 768);
    int*   i2s = (int*)(cv + 1024);
#pragma unroll
    for (int t = 0; t < 16; ++t) {
        float a1 = m1[t], a2 = m2[t], a3 = m3[t];
        int ai1 = i1[t], ai2 = i2[t];
        for (int msk = 8; msk >= 1; msk >>= 1) {
            float b1v = __shfl_xor(a1, msk);
            float b2v = __shfl_xor(a2, msk);
            float b3v = __shfl_xor(a3, msk);
            int bi1v = __shfl_xor(ai1, msk);
            int bi2v = __shfl_xor(ai2, msk);
            bool bw = (b1v < a1) || (b1v == a1 && bi1v < ai1);
            float w1 = bw ? b1v : a1;  int wi1 = bw ? bi1v : ai1;
            float w2 = bw ? b2v : a2;  int wi2 = bw ? bi2v : ai2;
            float w3 = bw ? b3v : a3;
            float l1 = bw ? a1 : b1v;  int li1 = bw ? ai1 : bi1v;
            float l2 = bw ? a2 : b2v;
            bool t2 = l1 < w2;
            a1 = w1; ai1 = wi1;
            a2 = t2 ? l1 : w2;  ai2 = t2 ? li1 : wi2;
            a3 = t2 ? fminf(w2, l2) : fminf(w3, l1);
        }
        if (l15 == 0) {
            int rloc = (t >> 2) * 16 + l4 * 4 + (t & 3);
            m1s[w * 64 + rloc] = a1;
            m2s[w * 64 + rloc] = a2;
            m3s[w * 64 + rloc] = a3;
            i1s[w * 64 + rloc] = ai1;
            i2s[w * 64 + rloc] = ai2;
        }
    }
    __syncthreads();

    // ---- cross-wave merge (two code halves) + flag taxonomy ----
    if (tid < 128) {
        int pg = tid >> 6, r = tid & 63;
        int wA = pg * 2, wB = pg * 2 + 1;
        float a1 = m1s[wA * 64 + r], a2 = m2s[wA * 64 + r], a3 = m3s[wA * 64 + r];
        int ai1 = i1s[wA * 64 + r], ai2 = i2s[wA * 64 + r];
        float b1v = m1s[wB * 64 + r], b2v = m2s[wB * 64 + r], b3v = m3s[wB * 64 + r];
        int bi1v = i1s[wB * 64 + r], bi2v = i2s[wB * 64 + r];
        bool bw = (b1v < a1) || (b1v == a1 && bi1v < ai1);
        float w1 = bw ? b1v : a1;  int wi1 = bw ? bi1v : ai1;
        float w2 = bw ? b2v : a2;  int wi2 = bw ? bi2v : ai2;
        float w3 = bw ? b3v : a3;
        float l1 = bw ? a1 : b1v;  int li1 = bw ? ai1 : bi1v;
        float l2 = bw ? a2 : b2v;
        bool t2 = l1 < w2;
        float f1 = w1;             int fi1 = wi1;
        float f2 = t2 ? l1 : w2;   int fi2 = t2 ? li1 : wi2;
        float f3 = t2 ? fminf(w2, l2) : fminf(w3, l1);

        int rowg = rb * 128 + pg * 64 + r;
        out_idx[rowg] = (float)fi1;
        if (f3 - f1 < MARGIN_BF) {                 // 3+ candidates: full exact rescan
            int pz = atomicAdd(&cnts[1], 1);
            if (pz < CAP_FULL) fulllist[pz] = rowg;
        } else if (f2 - f1 < MARGIN_BF) {          // exactly 2 candidates: exact duel
            int pz = atomicAdd(&cnts[0], 1);
            if (pz < CAP_DUEL) {
                duellist[pz] = ((unsigned long long)(unsigned)rowg << 32) |
                               ((unsigned)fi1 << 16) | (unsigned)fi2;
            } else {
                int pf = atomicAdd(&cnts[1], 1);
                if (pf < CAP_FULL) fulllist[pf] = rowg;
            }
        }
    }
}

// ---------------- exact duel: f32 chain (bit-identical to r2) on {i1, i2} ----------------
__global__ __launch_bounds__(256) void duel_kernel(
        const float* __restrict__ z, const float* __restrict__ emb,
        const float* __restrict__ rownorm, const float* __restrict__ cvec,
        const int* __restrict__ cnts, const unsigned long long* __restrict__ duellist,
        unsigned long long* __restrict__ rescored) {
    int n = cnts[0];
    if (n > CAP_DUEL) n = CAP_DUEL;
    for (int i = blockIdx.x * 256 + threadIdx.x; i < n; i += 64 * 256) {
        unsigned long long e = duellist[i];
        int row = (int)(e >> 32);
        int c1 = (int)((e >> 16) & 0xfffu);
        int c2 = (int)(e & 0xfffu);
        const float* zp = z + (size_t)row * D_DIM;
        const float* p1 = emb + (size_t)c1 * D_DIM;
        const float* p2 = emb + (size_t)c2 * D_DIM;
        float a1 = 0.f, a2 = 0.f;
#pragma unroll 8
        for (int d4 = 0; d4 < 64; ++d4) {          // d ascending, xyzw: r2 chain
            float4 zf = *(const float4*)&zp[d4 * 4];
            float4 e1 = *(const float4*)&p1[d4 * 4];
            float4 e2 = *(const float4*)&p2[d4 * 4];
            a1 = fmaf(zf.x, e1.x, a1); a1 = fmaf(zf.y, e1.y, a1);
            a1 = fmaf(zf.z, e1.z, a1); a1 = fmaf(zf.w, e1.w, a1);
            a2 = fmaf(zf.x, e2.x, a2); a2 = fmaf(zf.y, e2.y, a2);
            a2 = fmaf(zf.z, e2.z, a2); a2 = fmaf(zf.w, e2.w, a2);
        }
        float rn = rownorm[row];
        float d1 = __fadd_rn(__fsub_rn(rn, __fmul_rn(2.0f, a1)), cvec[c1]);
        float d2 = __fadd_rn(__fsub_rn(rn, __fmul_rn(2.0f, a2)), cvec[c2]);
        unsigned long long p1v = ((unsigned long long)__float_as_uint(d1) << 32) | (unsigned)c1;
        unsigned long long p2v = ((unsigned long long)__float_as_uint(d2) << 32) | (unsigned)c2;
        rescored[row] = p1v < p2v ? p1v : p2v;     // dist>0 -> f32 bits monotone
    }
}

// ---------------- full exact rescan (r2-chain; only 3-way-ambiguous rows) ----------------
__global__ __launch_bounds__(256) void rescore_kernel(
        const float* __restrict__ z, const float* __restrict__ emb,
        const float* __restrict__ rownorm, const float* __restrict__ cvec,
        const int* __restrict__ cnts, const int* __restrict__ fulllist,
        unsigned long long* __restrict__ rescored) {
    __shared__ float zs[16][256];
    __shared__ float sa[16];
    __shared__ int srow[16];
    const int tid = threadIdx.x;
    int cnt = cnts[1];
    if (cnt > CAP_FULL) cnt = CAP_FULL;
    const int nu = ((cnt + 15) >> 4) << 2;   // ceil(cnt/16) row-groups x 4 code-splits
    for (int uu = blockIdx.x; uu < nu; uu += gridDim.x) {
        int rg = uu >> 2, ks = uu & 3;
        __syncthreads();
        if (tid < 16) {
            int fi = rg * 16 + tid;
            int row = fulllist[fi < cnt ? fi : 0];
            srow[tid] = row;
            sa[tid] = rownorm[row];
        }
        __syncthreads();
#pragma unroll
        for (int i = 0; i < 4; ++i) {
            int u = i * 256 + tid;
            int r = u >> 6, d4 = u & 63;
            *(float4*)&zs[r][d4 * 4] = *(const float4*)&z[(size_t)srow[r] * D_DIM + d4 * 4];
        }
        __syncthreads();

        const int c0 = ks * 1024 + tid;
        float acc[16][4];
#pragma unroll
        for (int r = 0; r < 16; ++r)
#pragma unroll
            for (int j = 0; j < 4; ++j) acc[r][j] = 0.f;

        for (int ch = 0; ch < 8; ++ch) {
#pragma unroll
            for (int q = 0; q < 8; ++q) {
                float4 e0 = *(const float4*)&emb[(size_t)(c0      ) * D_DIM + ch * 32 + q * 4];
                float4 e1 = *(const float4*)&emb[(size_t)(c0 + 256) * D_DIM + ch * 32 + q * 4];
                float4 e2 = *(const float4*)&emb[(size_t)(c0 + 512) * D_DIM + ch * 32 + q * 4];
                float4 e3 = *(const float4*)&emb[(size_t)(c0 + 768) * D_DIM + ch * 32 + q * 4];
#pragma unroll
                for (int r = 0; r < 16; ++r) {
                    float4 zf = *(const float4*)&zs[r][ch * 32 + q * 4];
                    acc[r][0] = fmaf(zf.x, e0.x, acc[r][0]);
                    acc[r][0] = fmaf(zf.y, e0.y, acc[r][0]);
                    acc[r][0] = fmaf(zf.z, e0.z, acc[r][0]);
                    acc[r][0] = fmaf(zf.w, e0.w, acc[r][0]);
                    acc[r][1] = fmaf(zf.x, e1.x, acc[r][1]);
                    acc[r][1] = fmaf(zf.y, e1.y, acc[r][1]);
                    acc[r][1] = fmaf(zf.z, e1.z, acc[r][1]);
                    acc[r][1] = fmaf(zf.w, e1.w, acc[r][1]);
                    acc[r][2] = fmaf(zf.x, e2.x, acc[r][2]);
                    acc[r][2] = fmaf(zf.y, e2.y, acc[r][2]);
                    acc[r][2] = fmaf(zf.z, e2.z, acc[r][2]);
                    acc[r][2] = fmaf(zf.w, e2.w, acc[r][2]);
                    acc[r][3] = fmaf(zf.x, e3.x, acc[r][3]);
                    acc[r][3] = fmaf(zf.y, e3.y, acc[r][3]);
                    acc[r][3] = fmaf(zf.z, e3.z, acc[r][3]);
                    acc[r][3] = fmaf(zf.w, e3.w, acc[r][3]);
                }
            }
        }
        const float ck0 = cvec[c0], ck1 = cvec[c0 + 256];
        const float ck2 = cvec[c0 + 512], ck3 = cvec[c0 + 768];
#pragma unroll
        for (int r = 0; r < 16; ++r) {
            float d0 = __fadd_rn(__fsub_rn(sa[r], __fmul_rn(2.0f, acc[r][0])), ck0);
            float d1 = __fadd_rn(__fsub_rn(sa[r], __fmul_rn(2.0f, acc[r][1])), ck1);
            float d2 = __fadd_rn(__fsub_rn(sa[r], __fmul_rn(2.0f, acc[r][2])), ck2);
            float d3 = __fadd_rn(__fsub_rn(sa[r], __fmul_rn(2.0f, acc[r][3])), ck3);
            unsigned long long p0 = ((unsigned long long)__float_as_uint(d0) << 32) | (unsigned)(c0);
            unsigned long long p1 = ((unsigned long long)__float_as_uint(d1) << 32) | (unsigned)(c0 + 256);
            unsigned long long p2 = ((unsigned long long)__float_as_uint(d2) << 32) | (unsigned)(c0 + 512);
            unsigned long long p3 = ((unsigned long long)__float_as_uint(d3) << 32) | (unsigned)(c0 + 768);
            unsigned long long pa = p0 < p1 ? p0 : p1;
            unsigned long long pb = p2 < p3 ? p2 : p3;
            unsigned long long pm = pa < pb ? pa : pb;
            for (int msk = 32; msk >= 1; msk >>= 1) {
                unsigned long long qv = __shfl_xor(pm, msk);
                pm = qv < pm ? qv : pm;
            }
            if ((tid & 63) == 0) atomicMin(&rescored[srow[r]], pm);
        }
    }
}

// ---------------- writeback z_q_st + loss partials + fused index fixup (r9-verified) ----------------
__global__ __launch_bounds__(256) void writeback_kernel(
        const float* __restrict__ z, const float* __restrict__ emb,
        const unsigned long long* __restrict__ rescored,
        float* __restrict__ out_idx, float* __restrict__ out0,
        double* __restrict__ partials) {
    const int tid = threadIdx.x;
    const int base = blockIdx.x * 32;
    double acc = 0.0;
    for (int g = 0; g < 8; ++g) {
        int row = base + g * 4 + (tid >> 6);
        int d4 = tid & 63;
        unsigned long long rv = rescored[row];
        int idx;
        if (rv != ~0ull) {
            idx = (int)(unsigned)(rv & 0xffffffffull);
            if (d4 == 0) out_idx[row] = (float)idx;
        } else {
            idx = (int)out_idx[row];
        }
        float4 q4 = *(const float4*)&emb[(size_t)idx * D_DIM + d4 * 4];
        float4 z4 = *(const float4*)&z[(size_t)row * D_DIM + d4 * 4];
        float4 o;
        float dx;
        dx = q4.x - z4.x; o.x = z4.x + dx; acc += (double)dx * dx;
        dx = q4.y - z4.y; o.y = z4.y + dx; acc += (double)dx * dx;
        dx = q4.z - z4.z; o.z = z4.z + dx; acc += (double)dx * dx;
        dx = q4.w - z4.w; o.w = z4.w + dx; acc += (double)dx * dx;
        *(float4*)&out0[(size_t)row * D_DIM + d4 * 4] = o;
    }
    for (int m = 32; m >= 1; m >>= 1) acc += __shfl_xor(acc, m);
    __shared__ double sd[4];
    if ((tid & 63) == 0) sd[tid >> 6] = acc;
    __syncthreads();
    if (tid == 0) partials[blockIdx.x] = (sd[0] + sd[1]) + (sd[2] + sd[3]);
}

__global__ void finalize_kernel(const double* __restrict__ partials, float* __restrict__ out_loss) {
    __shared__ double sd[256];
    const int tid = threadIdx.x;
    double a = 0.0;
    for (int i = tid; i < 2048; i += 256) a += partials[i];
    sd[tid] = a;
    __syncthreads();
    for (int s = 128; s > 0; s >>= 1) {
        if (tid < s) sd[tid] += sd[tid + s];
        __syncthreads();
    }
    if (tid == 0) {
        double m = sd[0] / 16777216.0;
        out_loss[0] = (float)(m + 0.25 * m);
    }
}

extern "C" void kernel_launch(void* const* d_in, const int* in_sizes, int n_in,
                              void* d_out, int out_size, void* d_ws, size_t ws_size,
                              hipStream_t stream) {
    const float* z = (const float*)d_in[0];
    const float* emb = (const float*)d_in[1];
    float* out0 = (float*)d_out;
    float* out_loss = out0 + (size_t)N_ROWS * D_DIM;
    float* out_idx = out_loss + 1;

    char* ws = (char*)d_ws;
    float* rownorm = (float*)ws;
    float* cvec = (float*)(ws + 262144);
    unsigned short* emb_perm = (unsigned short*)(ws + 278528);
    int* cnts = (int*)(ws + 2375680);
    int* fulllist = (int*)(ws + 2375936);
    unsigned long long* duellist = (unsigned long long*)(ws + 2408704);
    unsigned long long* rescored = (unsigned long long*)(ws + 2605312);
    double* partials = (double*)(ws + 3129600);

    // 33.5 MB z_perm scratch inside d_out (fully overwritten by writeback_kernel)
    unsigned short* z_perm = (unsigned short*)d_out;

    cvt_emb_kernel<<<576, 256, 0, stream>>>(emb, emb_perm, cvec, cnts);
    cvt_z_kernel<<<9216, 256, 0, stream>>>(z, z_perm, rownorm, rescored);
    phaseB_kernel<<<512, 256, 0, stream>>>(z_perm, emb_perm, cvec, out_idx, cnts, fulllist, duellist);
    rescore_kernel<<<256, 256, 0, stream>>>(z, emb, rownorm, cvec, cnts, fulllist, rescored);
    duel_kernel<<<64, 256, 0, stream>>>(z, emb, rownorm, cvec, cnts, duellist, rescored);
    writeback_kernel<<<N_ROWS / 32, 256, 0, stream>>>(z, emb, rescored, out_idx, out0, partials);
    finalize_kernel<<<1, 256, 0, stream>>>(partials, out_loss);
}

// Round 13
// 390.392 us; speedup vs baseline: 1.2227x; 1.2227x over previous
//
#include <hip/hip_runtime.h>

#define N_ROWS 65536
#define K_CODES 4096
#define D_DIM 256
#define MARGIN_BF 4.5e-5f
#define CAP_DUEL 24576
#define CAP_FULL 8192

typedef __attribute__((ext_vector_type(8))) _Float16 f16x8;
typedef __attribute__((ext_vector_type(4))) float f32x4;

// ---------------- ws layout ----------------
// [0]        float  rownorm[65536]      256 KB
// [262144]   float  cvec[4096]           16 KB
// [278528]   ushort emb_perm[4096*256]    2 MB   (f16 x4096, cf-major stream-linear)
// [2375680]  int    cnts[2]  (0=duel, 1=full)
// [2375936]  int    fulllist[8192]       32 KB
// [2408704]  u64    duellist[24576]     192 KB
// [2605312]  u64    rescored[65536]     512 KB
// [3129600]  double partials[2048]       16 KB
// z_perm (33.5 MB) lives in d_out as scratch; writeback overwrites d_out fully.

union f16u { _Float16 h; unsigned short u; };

static __device__ __forceinline__ unsigned int pack2(float a, float b) {
    f16u x, y; x.h = (_Float16)a; y.h = (_Float16)b;
    return (unsigned)x.u | ((unsigned)y.u << 16);
}

// ---------------- r2-verified norm chain (verbatim body, block-offset) ----------------
static __device__ __forceinline__ void norm_body(const float* __restrict__ src,
                                                 float* __restrict__ dst, int bi, int tid) {
    int row = bi * 64 + (tid >> 2);
    int q = tid & 3;
    const float* p = src + (size_t)row * D_DIM;
    double acc = 0.0;
#pragma unroll 4
    for (int it = 0; it < 16; ++it) {
        float4 v = *(const float4*)&p[(q + 4 * it) * 4];
        float a = v.x * v.x, b = v.y * v.y, c = v.z * v.z, d = v.w * v.w;
        acc += (double)a; acc += (double)b; acc += (double)c; acc += (double)d;
    }
    acc += __shfl_xor(acc, 1);
    acc += __shfl_xor(acc, 2);
    if (q == 0) dst[row] = (float)acc;
}

// ---------------- emb -> f16(x4096), cf-major stream-linear + emb-norm + cnt clear ----------------
// frag f = h*1024 + step*16 + cf*8 + d8 ; lane part holds
// emb[h*2048 + step*32 + cf*16 + (lane&15)][d8*32 + (lane>>4)*8 + 0..7] * 4096
__global__ __launch_bounds__(256) void cvt_emb_kernel(const float* __restrict__ emb,
                                                      unsigned short* __restrict__ emb_perm,
                                                      float* __restrict__ cvec,
                                                      int* __restrict__ cnts) {
    if (blockIdx.x >= 512) {
        if (blockIdx.x == 512 && threadIdx.x < 2) cnts[threadIdx.x] = 0;
        norm_body(emb, cvec, blockIdx.x - 512, threadIdx.x);
        return;
    }
    int gid = blockIdx.x * 256 + threadIdx.x;     // 131072 16B units
    int lane = gid & 63;
    int f = gid >> 6;
    int d8 = f & 7;
    int cf = (f >> 3) & 1;
    int step = (f >> 4) & 63;
    int h = f >> 10;
    int code = h * 2048 + step * 32 + cf * 16 + (lane & 15);
    int d0 = d8 * 32 + (lane >> 4) * 8;
    const float* p = emb + (size_t)code * D_DIM + d0;
    float4 v0 = *(const float4*)p;
    float4 v1 = *(const float4*)(p + 4);
    uint4 o;
    o.x = pack2(v0.x * 4096.0f, v0.y * 4096.0f);
    o.y = pack2(v0.z * 4096.0f, v0.w * 4096.0f);
    o.z = pack2(v1.x * 4096.0f, v1.y * 4096.0f);
    o.w = pack2(v1.z * 4096.0f, v1.w * 4096.0f);
    *(uint4*)((char*)emb_perm + (size_t)gid * 16) = o;
}

// ---------------- z -> f16 fragment-linear + z-norm + rescored clear (r11-verified) ----------------
__global__ __launch_bounds__(256) void cvt_z_kernel(const float* __restrict__ z,
                                                    unsigned short* __restrict__ z_perm,
                                                    float* __restrict__ rownorm,
                                                    unsigned long long* __restrict__ rescored) {
    if (blockIdx.x >= 8192) {
        norm_body(z, rownorm, blockIdx.x - 8192, threadIdx.x);
        return;
    }
    if (blockIdx.x < 256) rescored[blockIdx.x * 256 + threadIdx.x] = ~0ull;
    int ft = blockIdx.x * 256 + threadIdx.x;      // 2097152 frag-lanes
    int lane = ft & 63;
    int rf = (ft >> 6) & 3;
    int d8 = (ft >> 8) & 7;
    int rg = ft >> 11;
    int row = rg * 64 + rf * 16 + (lane & 15);
    int d0 = d8 * 32 + (lane >> 4) * 8;
    const float* p = z + (size_t)row * D_DIM + d0;
    float4 v0 = *(const float4*)p;
    float4 v1 = *(const float4*)(p + 4);
    uint4 o;
    o.x = pack2(v0.x, v0.y);
    o.y = pack2(v0.z, v0.w);
    o.z = pack2(v1.x, v1.y);
    o.w = pack2(v1.z, v1.w);
    *(uint4*)((char*)z_perm + (size_t)ft * 16) = o;
}

// ---------------- phase B: B-streaming f16 MFMA argmin, top-3 + packed indices ----------------
// Reg budget: A 128 + ring 16 + acc 16 + state(m1,m2,m3,pk) 64 + misc ~15 = ~240 (< 256, 2 w/SIMD)
__global__ __launch_bounds__(256, 2) void phaseB_kernel(
        const unsigned short* __restrict__ z_perm, const unsigned short* __restrict__ emb_perm,
        const float* __restrict__ cvec, float* __restrict__ out_idx,
        int* __restrict__ cnts, int* __restrict__ fulllist,
        unsigned long long* __restrict__ duellist) {
    __shared__ float cv[4096];     // 16 KB; reused as merge scratch after the loop

    const int tid = threadIdx.x;
    const int lane = tid & 63;
    const int w = tid >> 6;
    const int pp = w >> 1;         // row group
    const int h = w & 1;           // code half
    const int l15 = lane & 15, l4 = lane >> 4;
    const int rb = blockIdx.x;     // 512 blocks x 128 rows

    // ---- cvec -> LDS ----
#pragma unroll
    for (int i = 0; i < 4; ++i) {
        int idx = i * 1024 + tid * 4;
        *(float4*)&cv[idx] = *(const float4*)&cvec[idx];
    }

    // ---- A (64 rows) into registers: 32 frags = 128 VGPR ----
    f16x8 A[8][4];
    {
        const char* zsrc = (const char*)z_perm + (size_t)(rb * 2 + pp) * 32768 + lane * 16;
#pragma unroll
        for (int d8 = 0; d8 < 8; ++d8)
#pragma unroll
            for (int rf = 0; rf < 4; ++rf)
                A[d8][rf] = *(const f16x8*)(zsrc + (d8 * 4 + rf) * 1024);
    }
    __syncthreads();               // cv ready

    // ---- B stream: 4-slot x 1-frag ring, depth-3 prefetch; frag idx = cf*8 + d8 ----
    const char* bq = (const char*)emb_perm + (size_t)h * 1048576 + lane * 16;
    f16x8 R0, R1, R2, R3;
    R0 = *(const f16x8*)(bq);
    R1 = *(const f16x8*)(bq + 1024);
    R2 = *(const f16x8*)(bq + 2048);

    float m1[16], m2[16], m3[16];
    unsigned pk[16];               // (i1<<16)|i2
#pragma unroll
    for (int t = 0; t < 16; ++t) { m1[t] = 3.4e38f; m2[t] = 3.4e38f; m3[t] = 3.4e38f; pk[t] = 0; }

    f32x4 acc[4];

    for (int step = 0; step < 64; ++step) {
        const int kb = h * 2048 + step * 32;
#pragma unroll
        for (int cf = 0; cf < 2; ++cf) {
            const unsigned cg = (unsigned)(kb + cf * 16 + l15);
            const unsigned cg16 = cg << 16;
            const float ck = cv[cg];
#pragma unroll
            for (int rf = 0; rf < 4; ++rf) acc[rf] = (f32x4){0.f, 0.f, 0.f, 0.f};
            // Tail prefetch past the half (or buffer end) reads mapped ws bytes
            // into dead regs, never consumed. Safe.
#pragma unroll
            for (int d8 = 0; d8 < 8; ++d8) {
                const int idx = cf * 8 + d8;
                f16x8 b;
                switch (idx & 3) {
                    case 0: b = R0; break;
                    case 1: b = R1; break;
                    case 2: b = R2; break;
                    default: b = R3; break;
                }
                const char* pf = bq + (idx + 3) * 1024;
                switch ((idx + 3) & 3) {
                    case 0: R0 = *(const f16x8*)pf; break;
                    case 1: R1 = *(const f16x8*)pf; break;
                    case 2: R2 = *(const f16x8*)pf; break;
                    default: R3 = *(const f16x8*)pf; break;
                }
#pragma unroll
                for (int rf = 0; rf < 4; ++rf)
                    acc[rf] = __builtin_amdgcn_mfma_f32_16x16x32_f16(A[d8][rf], b, acc[rf], 0, 0, 0);
            }
            // ---- epilogue cf: running top-3 values + packed top-2 indices ----
#pragma unroll
            for (int rf = 0; rf < 4; ++rf)
#pragma unroll
                for (int j = 0; j < 4; ++j) {
                    // acc = z.(4096 e); -2*dot = acc * -2^-11 (exact scale)
                    float d = fmaf(-4.8828125e-4f, acc[rf][j], ck);
                    const int t = rf * 4 + j;
                    bool lt1 = d < m1[t];
                    bool lt2 = d < m2[t];
                    unsigned pa = cg16 | (pk[t] >> 16);
                    unsigned pb = (pk[t] & 0xffff0000u) | cg;
                    pk[t] = lt1 ? pa : (lt2 ? pb : pk[t]);
                    m3[t] = __builtin_amdgcn_fmed3f(d, m2[t], m3[t]);
                    m2[t] = __builtin_amdgcn_fmed3f(d, m1[t], m2[t]);
                    m1[t] = fminf(m1[t], d);
                }
        }
        bq += 16384;
    }

    // ---- per-wave merge across the 16 column-lanes (top-3 sorted-merge, r12-verified) ----
    __syncthreads();               // cv dead; reuse as merge scratch
    float* m1s = cv;               // [4][64]
    float* m2s = cv + 256;
    float* m3s = cv + 512;
    int*   i1s = (int*)(cv + 768);
    int*   i2s = (int*)(cv + 1024);
#pragma unroll
    for (int t = 0; t < 16; ++t) {
        float a1 = m1[t], a2 = m2[t], a3 = m3[t];
        int ai1 = (int)(pk[t] >> 16), ai2 = (int)(pk[t] & 0xffffu);
        for (int msk = 8; msk >= 1; msk >>= 1) {
            float b1v = __shfl_xor(a1, msk);
            float b2v = __shfl_xor(a2, msk);
            float b3v = __shfl_xor(a3, msk);
            int bi1v = __shfl_xor(ai1, msk);
            int bi2v = __shfl_xor(ai2, msk);
            bool bw = (b1v < a1) || (b1v == a1 && bi1v < ai1);
            float w1 = bw ? b1v : a1;  int wi1 = bw ? bi1v : ai1;
            float w2 = bw ? b2v : a2;  int wi2 = bw ? bi2v : ai2;
            float w3 = bw ? b3v : a3;
            float l1 = bw ? a1 : b1v;  int li1 = bw ? ai1 : bi1v;
            float l2 = bw ? a2 : b2v;
            bool t2 = l1 < w2;
            a1 = w1; ai1 = wi1;
            a2 = t2 ? l1 : w2;  ai2 = t2 ? li1 : wi2;
            a3 = t2 ? fminf(w2, l2) : fminf(w3, l1);
        }
        if (l15 == 0) {
            int rloc = (t >> 2) * 16 + l4 * 4 + (t & 3);
            m1s[w * 64 + rloc] = a1;
            m2s[w * 64 + rloc] = a2;
            m3s[w * 64 + rloc] = a3;
            i1s[w * 64 + rloc] = ai1;
            i2s[w * 64 + rloc] = ai2;
        }
    }
    __syncthreads();

    // ---- cross-wave merge (two code halves) + flag taxonomy (r12-verified) ----
    if (tid < 128) {
        int pg = tid >> 6, r = tid & 63;
        int wA = pg * 2, wB = pg * 2 + 1;
        float a1 = m1s[wA * 64 + r], a2 = m2s[wA * 64 + r], a3 = m3s[wA * 64 + r];
        int ai1 = i1s[wA * 64 + r], ai2 = i2s[wA * 64 + r];
        float b1v = m1s[wB * 64 + r], b2v = m2s[wB * 64 + r], b3v = m3s[wB * 64 + r];
        int bi1v = i1s[wB * 64 + r], bi2v = i2s[wB * 64 + r];
        bool bw = (b1v < a1) || (b1v == a1 && bi1v < ai1);
        float w1 = bw ? b1v : a1;  int wi1 = bw ? bi1v : ai1;
        float w2 = bw ? b2v : a2;  int wi2 = bw ? bi2v : ai2;
        float w3 = bw ? b3v : a3;
        float l1 = bw ? a1 : b1v;  int li1 = bw ? ai1 : bi1v;
        float l2 = bw ? a2 : b2v;
        bool t2 = l1 < w2;
        float f1 = w1;             int fi1 = wi1;
        float f2 = t2 ? l1 : w2;   int fi2 = t2 ? li1 : wi2;
        float f3 = t2 ? fminf(w2, l2) : fminf(w3, l1);

        int rowg = rb * 128 + pg * 64 + r;
        out_idx[rowg] = (float)fi1;
        if (f3 - f1 < MARGIN_BF) {                 // 3+ candidates: full exact rescan
            int pz = atomicAdd(&cnts[1], 1);
            if (pz < CAP_FULL) fulllist[pz] = rowg;
        } else if (f2 - f1 < MARGIN_BF) {          // exactly 2 candidates: exact duel
            int pz = atomicAdd(&cnts[0], 1);
            if (pz < CAP_DUEL) {
                duellist[pz] = ((unsigned long long)(unsigned)rowg << 32) |
                               ((unsigned)fi1 << 16) | (unsigned)fi2;
            } else {
                int pf = atomicAdd(&cnts[1], 1);
                if (pf < CAP_FULL) fulllist[pf] = rowg;
            }
        }
    }
}

// ---------------- exact duel: f32 chain (bit-identical to r2) on {i1, i2} ----------------
__global__ __launch_bounds__(256) void duel_kernel(
        const float* __restrict__ z, const float* __restrict__ emb,
        const float* __restrict__ rownorm, const float* __restrict__ cvec,
        const int* __restrict__ cnts, const unsigned long long* __restrict__ duellist,
        unsigned long long* __restrict__ rescored) {
    int n = cnts[0];
    if (n > CAP_DUEL) n = CAP_DUEL;
    for (int i = blockIdx.x * 256 + threadIdx.x; i < n; i += 64 * 256) {
        unsigned long long e = duellist[i];
        int row = (int)(e >> 32);
        int c1 = (int)((e >> 16) & 0xfffu);
        int c2 = (int)(e & 0xfffu);
        const float* zp = z + (size_t)row * D_DIM;
        const float* p1 = emb + (size_t)c1 * D_DIM;
        const float* p2 = emb + (size_t)c2 * D_DIM;
        float a1 = 0.f, a2 = 0.f;
#pragma unroll 8
        for (int d4 = 0; d4 < 64; ++d4) {          // d ascending, xyzw: r2 chain
            float4 zf = *(const float4*)&zp[d4 * 4];
            float4 e1 = *(const float4*)&p1[d4 * 4];
            float4 e2 = *(const float4*)&p2[d4 * 4];
            a1 = fmaf(zf.x, e1.x, a1); a1 = fmaf(zf.y, e1.y, a1);
            a1 = fmaf(zf.z, e1.z, a1); a1 = fmaf(zf.w, e1.w, a1);
            a2 = fmaf(zf.x, e2.x, a2); a2 = fmaf(zf.y, e2.y, a2);
            a2 = fmaf(zf.z, e2.z, a2); a2 = fmaf(zf.w, e2.w, a2);
        }
        float rn = rownorm[row];
        float d1 = __fadd_rn(__fsub_rn(rn, __fmul_rn(2.0f, a1)), cvec[c1]);
        float d2 = __fadd_rn(__fsub_rn(rn, __fmul_rn(2.0f, a2)), cvec[c2]);
        unsigned long long p1v = ((unsigned long long)__float_as_uint(d1) << 32) | (unsigned)c1;
        unsigned long long p2v = ((unsigned long long)__float_as_uint(d2) << 32) | (unsigned)c2;
        rescored[row] = p1v < p2v ? p1v : p2v;     // dist>0 -> f32 bits monotone
    }
}

// ---------------- full exact rescan (r2-chain; only 3-way-ambiguous rows) ----------------
__global__ __launch_bounds__(256) void rescore_kernel(
        const float* __restrict__ z, const float* __restrict__ emb,
        const float* __restrict__ rownorm, const float* __restrict__ cvec,
        const int* __restrict__ cnts, const int* __restrict__ fulllist,
        unsigned long long* __restrict__ rescored) {
    __shared__ float zs[16][256];
    __shared__ float sa[16];
    __shared__ int srow[16];
    const int tid = threadIdx.x;
    int cnt = cnts[1];
    if (cnt > CAP_FULL) cnt = CAP_FULL;
    const int nu = ((cnt + 15) >> 4) << 2;   // ceil(cnt/16) row-groups x 4 code-splits
    for (int uu = blockIdx.x; uu < nu; uu += gridDim.x) {
        int rg = uu >> 2, ks = uu & 3;
        __syncthreads();
        if (tid < 16) {
            int fi = rg * 16 + tid;
            int row = fulllist[fi < cnt ? fi : 0];
            srow[tid] = row;
            sa[tid] = rownorm[row];
        }
        __syncthreads();
#pragma unroll
        for (int i = 0; i < 4; ++i) {
            int u = i * 256 + tid;
            int r = u >> 6, d4 = u & 63;
            *(float4*)&zs[r][d4 * 4] = *(const float4*)&z[(size_t)srow[r] * D_DIM + d4 * 4];
        }
        __syncthreads();

        const int c0 = ks * 1024 + tid;
        float acc[16][4];
#pragma unroll
        for (int r = 0; r < 16; ++r)
#pragma unroll
            for (int j = 0; j < 4; ++j) acc[r][j] = 0.f;

        for (int ch = 0; ch < 8; ++ch) {
#pragma unroll
            for (int q = 0; q < 8; ++q) {
                float4 e0 = *(const float4*)&emb[(size_t)(c0      ) * D_DIM + ch * 32 + q * 4];
                float4 e1 = *(const float4*)&emb[(size_t)(c0 + 256) * D_DIM + ch * 32 + q * 4];
                float4 e2 = *(const float4*)&emb[(size_t)(c0 + 512) * D_DIM + ch * 32 + q * 4];
                float4 e3 = *(const float4*)&emb[(size_t)(c0 + 768) * D_DIM + ch * 32 + q * 4];
#pragma unroll
                for (int r = 0; r < 16; ++r) {
                    float4 zf = *(const float4*)&zs[r][ch * 32 + q * 4];
                    acc[r][0] = fmaf(zf.x, e0.x, acc[r][0]);
                    acc[r][0] = fmaf(zf.y, e0.y, acc[r][0]);
                    acc[r][0] = fmaf(zf.z, e0.z, acc[r][0]);
                    acc[r][0] = fmaf(zf.w, e0.w, acc[r][0]);
                    acc[r][1] = fmaf(zf.x, e1.x, acc[r][1]);
                    acc[r][1] = fmaf(zf.y, e1.y, acc[r][1]);
                    acc[r][1] = fmaf(zf.z, e1.z, acc[r][1]);
                    acc[r][1] = fmaf(zf.w, e1.w, acc[r][1]);
                    acc[r][2] = fmaf(zf.x, e2.x, acc[r][2]);
                    acc[r][2] = fmaf(zf.y, e2.y, acc[r][2]);
                    acc[r][2] = fmaf(zf.z, e2.z, acc[r][2]);
                    acc[r][2] = fmaf(zf.w, e2.w, acc[r][2]);
                    acc[r][3] = fmaf(zf.x, e3.x, acc[r][3]);
                    acc[r][3] = fmaf(zf.y, e3.y, acc[r][3]);
                    acc[r][3] = fmaf(zf.z, e3.z, acc[r][3]);
                    acc[r][3] = fmaf(zf.w, e3.w, acc[r][3]);
                }
            }
        }
        const float ck0 = cvec[c0], ck1 = cvec[c0 + 256];
        const float ck2 = cvec[c0 + 512], ck3 = cvec[c0 + 768];
#pragma unroll
        for (int r = 0; r < 16; ++r) {
            float d0 = __fadd_rn(__fsub_rn(sa[r], __fmul_rn(2.0f, acc[r][0])), ck0);
            float d1 = __fadd_rn(__fsub_rn(sa[r], __fmul_rn(2.0f, acc[r][1])), ck1);
            float d2 = __fadd_rn(__fsub_rn(sa[r], __fmul_rn(2.0f, acc[r][2])), ck2);
            float d3 = __fadd_rn(__fsub_rn(sa[r], __fmul_rn(2.0f, acc[r][3])), ck3);
            unsigned long long p0 = ((unsigned long long)__float_as_uint(d0) << 32) | (unsigned)(c0);
            unsigned long long p1 = ((unsigned long long)__float_as_uint(d1) << 32) | (unsigned)(c0 + 256);
            unsigned long long p2 = ((unsigned long long)__float_as_uint(d2) << 32) | (unsigned)(c0 + 512);
            unsigned long long p3 = ((unsigned long long)__float_as_uint(d3) << 32) | (unsigned)(c0 + 768);
            unsigned long long pa = p0 < p1 ? p0 : p1;
            unsigned long long pb = p2 < p3 ? p2 : p3;
            unsigned long long pm = pa < pb ? pa : pb;
            for (int msk = 32; msk >= 1; msk >>= 1) {
                unsigned long long qv = __shfl_xor(pm, msk);
                pm = qv < pm ? qv : pm;
            }
            if ((tid & 63) == 0) atomicMin(&rescored[srow[r]], pm);
        }
    }
}

// ---------------- writeback z_q_st + loss partials + fused index fixup (r9-verified) ----------------
__global__ __launch_bounds__(256) void writeback_kernel(
        const float* __restrict__ z, const float* __restrict__ emb,
        const unsigned long long* __restrict__ rescored,
        float* __restrict__ out_idx, float* __restrict__ out0,
        double* __restrict__ partials) {
    const int tid = threadIdx.x;
    const int base = blockIdx.x * 32;
    double acc = 0.0;
    for (int g = 0; g < 8; ++g) {
        int row = base + g * 4 + (tid >> 6);
        int d4 = tid & 63;
        unsigned long long rv = rescored[row];
        int idx;
        if (rv != ~0ull) {
            idx = (int)(unsigned)(rv & 0xffffffffull);
            if (d4 == 0) out_idx[row] = (float)idx;
        } else {
            idx = (int)out_idx[row];
        }
        float4 q4 = *(const float4*)&emb[(size_t)idx * D_DIM + d4 * 4];
        float4 z4 = *(const float4*)&z[(size_t)row * D_DIM + d4 * 4];
        float4 o;
        float dx;
        dx = q4.x - z4.x; o.x = z4.x + dx; acc += (double)dx * dx;
        dx = q4.y - z4.y; o.y = z4.y + dx; acc += (double)dx * dx;
        dx = q4.z - z4.z; o.z = z4.z + dx; acc += (double)dx * dx;
        dx = q4.w - z4.w; o.w = z4.w + dx; acc += (double)dx * dx;
        *(float4*)&out0[(size_t)row * D_DIM + d4 * 4] = o;
    }
    for (int m = 32; m >= 1; m >>= 1) acc += __shfl_xor(acc, m);
    __shared__ double sd[4];
    if ((tid & 63) == 0) sd[tid >> 6] = acc;
    __syncthreads();
    if (tid == 0) partials[blockIdx.x] = (sd[0] + sd[1]) + (sd[2] + sd[3]);
}

__global__ void finalize_kernel(const double* __restrict__ partials, float* __restrict__ out_loss) {
    __shared__ double sd[256];
    const int tid = threadIdx.x;
    double a = 0.0;
    for (int i = tid; i < 2048; i += 256) a += partials[i];
    sd[tid] = a;
    __syncthreads();
    for (int s = 128; s > 0; s >>= 1) {
        if (tid < s) sd[tid] += sd[tid + s];
        __syncthreads();
    }
    if (tid == 0) {
        double m = sd[0] / 16777216.0;
        out_loss[0] = (float)(m + 0.25 * m);
    }
}

extern "C" void kernel_launch(void* const* d_in, const int* in_sizes, int n_in,
                              void* d_out, int out_size, void* d_ws, size_t ws_size,
                              hipStream_t stream) {
    const float* z = (const float*)d_in[0];
    const float* emb = (const float*)d_in[1];
    float* out0 = (float*)d_out;
    float* out_loss = out0 + (size_t)N_ROWS * D_DIM;
    float* out_idx = out_loss + 1;

    char* ws = (char*)d_ws;
    float* rownorm = (float*)ws;
    float* cvec = (float*)(ws + 262144);
    unsigned short* emb_perm = (unsigned short*)(ws + 278528);
    int* cnts = (int*)(ws + 2375680);
    int* fulllist = (int*)(ws + 2375936);
    unsigned long long* duellist = (unsigned long long*)(ws + 2408704);
    unsigned long long* rescored = (unsigned long long*)(ws + 2605312);
    double* partials = (double*)(ws + 3129600);

    // 33.5 MB z_perm scratch inside d_out (fully overwritten by writeback_kernel)
    unsigned short* z_perm = (unsigned short*)d_out;

    cvt_emb_kernel<<<576, 256, 0, stream>>>(emb, emb_perm, cvec, cnts);
    cvt_z_kernel<<<9216, 256, 0, stream>>>(z, z_perm, rownorm, rescored);
    phaseB_kernel<<<512, 256, 0, stream>>>(z_perm, emb_perm, cvec, out_idx, cnts, fulllist, duellist);
    rescore_kernel<<<256, 256, 0, stream>>>(z, emb, rownorm, cvec, cnts, fulllist, rescored);
    duel_kernel<<<64, 256, 0, stream>>>(z, emb, rownorm, cvec, cnts, duellist, rescored);
    writeback_kernel<<<N_ROWS / 32, 256, 0, stream>>>(z, emb, rescored, out_idx, out0, partials);
    finalize_kernel<<<1, 256, 0, stream>>>(partials, out_loss);
}